// Round 5
// baseline (537.362 us; speedup 1.0000x reference)
//
#include <hip/hip_runtime.h>

typedef float f32x4 __attribute__((ext_vector_type(4)));

constexpr int T_ = 32768;
constexpr int D_ = 2048;
constexpr int E_ = 64;
constexpr int KSEL = 6;
constexpr float ROUTE_SCALE_ = 1.0f;

constexpr int CK = 64;            // k per chunk
constexpr int KW = D_ / 4;        // 512 k per wave (4 waves split K)
constexpr int NCHW = KW / CK;     // 8 chunks per wave
constexpr int STR = 66;           // padded floats per LDS row (bank-spread, 8B-aligned)

// WT[k][e] = W[e][k]  (contiguous e for s_load_dwordx16 batches)
__global__ void wtrans_kernel(const float* __restrict__ W, float* __restrict__ WT) {
  int t = blockIdx.x * 256 + threadIdx.x;   // 131072 = 2048k * 64e
  int k = t >> 6, e = t & 63;
  WT[t] = W[(size_t)e * D_ + k];
}

__launch_bounds__(256, 2)
__global__ void gate_kernel(const float* __restrict__ x, const float* __restrict__ WT,
                            float* __restrict__ out) {
  __shared__ float XT[4 * 64 * STR];        // 67584 B; 4 wave-private tiles

  const int tid = threadIdx.x;
  const int lane = tid & 63;
  const int wv = tid >> 6;
  const int r0 = blockIdx.x * 64;           // 64 rows per block, all waves share rows
  const int k0w = wv * KW;                  // this wave's K range
  float* xt = &XT[wv * 64 * STR];

  // 64 expert accumulators per lane (lane = row r0+lane), static-indexed via f32x4[16]
  f32x4 acc[16];
#pragma unroll
  for (int i = 0; i < 16; ++i) acc[i] = (f32x4){0.f, 0.f, 0.f, 0.f};

  // staging: inst i covers rows [i*4, i*4+4), lane: row = i*4 + (lane>>4), seg = lane&15
  const int srow = lane >> 4;
  const int sseg = lane & 15;
  f32x4 xr[16];                             // prefetch regs (one chunk)

  auto gload = [&](int c) {
    const float* base = x + (size_t)r0 * D_ + k0w + c * CK;
#pragma unroll
    for (int i = 0; i < 16; ++i)
      xr[i] = *(const f32x4*)(base + (size_t)(i * 4 + srow) * D_ + sseg * 4);
  };
  auto sstore = [&]() {
#pragma unroll
    for (int i = 0; i < 16; ++i) {
      float2* p2 = (float2*)&xt[(i * 4 + srow) * STR + sseg * 4];
      p2[0] = make_float2(xr[i].x, xr[i].y);
      p2[1] = make_float2(xr[i].z, xr[i].w);
    }
  };

  gload(0);
  for (int c = 0; c < NCHW; ++c) {
    sstore();                               // write chunk c to LDS (wave-private)
    if (c + 1 < NCHW) gload(c + 1);         // prefetch next chunk; FMA hides HBM latency
    const float* wcol = WT + (size_t)(k0w + c * CK) * E_;   // uniform address
    for (int k4 = 0; k4 < 16; ++k4) {       // 4 k per iter; body ~280 insts (I$-friendly)
      const float* xv2 = &xt[lane * STR + k4 * 4];
      float2 xa = *(const float2*)(xv2);
      float2 xb = *(const float2*)(xv2 + 2);
      float xk[4] = {xa.x, xa.y, xb.x, xb.y};
      const float* wk = wcol + k4 * 4 * E_;
#pragma unroll
      for (int kk = 0; kk < 4; ++kk) {
        const float xv = xk[kk];
        const float* we = wk + kk * E_;     // uniform -> s_load_dwordx16 batches
#pragma unroll
        for (int q = 0; q < 16; ++q) {
          acc[q][0] = fmaf(we[4 * q + 0], xv, acc[q][0]);
          acc[q][1] = fmaf(we[4 * q + 1], xv, acc[q][1]);
          acc[q][2] = fmaf(we[4 * q + 2], xv, acc[q][2]);
          acc[q][3] = fmaf(we[4 * q + 3], xv, acc[q][3]);
        }
      }
    }
  }

  // dump partial logits (this wave's K-quarter) into its tile: xt[lane][e]
#pragma unroll
  for (int q = 0; q < 16; ++q) {
    float2* p2 = (float2*)&xt[lane * STR + 4 * q];
    p2[0] = make_float2(acc[q][0], acc[q][1]);
    p2[1] = make_float2(acc[q][2], acc[q][3]);
  }
  __syncthreads();

  // reduce 4 K-partials + proven shuffle epilogue; wave wv owns rows [wv*16, wv*16+16)
  float* outI = out;
  float* outW = out + (size_t)T_ * KSEL;
  for (int rr = 0; rr < 16; ++rr) {
    const int r = wv * 16 + rr;
    float lg = XT[0 * 64 * STR + r * STR + lane] + XT[1 * 64 * STR + r * STR + lane] +
               XT[2 * 64 * STR + r * STR + lane] + XT[3 * 64 * STR + r * STR + lane];
    float mx = lg;
#pragma unroll
    for (int off = 32; off; off >>= 1) mx = fmaxf(mx, __shfl_xor(mx, off, 64));
    const float p = expf(lg - mx);
    float ssum = p;
#pragma unroll
    for (int off = 32; off; off >>= 1) ssum += __shfl_xor(ssum, off, 64);
    float prob = p / ssum;

    const int rg = r0 + r;
#pragma unroll
    for (int kk = 0; kk < KSEL; ++kk) {
      float v = prob; int idx = lane;
#pragma unroll
      for (int off = 32; off; off >>= 1) {
        float ov = __shfl_xor(v, off, 64);
        int oi = __shfl_xor(idx, off, 64);
        if (ov > v || (ov == v && oi < idx)) { v = ov; idx = oi; }
      }
      const float wsel = __shfl(lg, idx, 64);
      if (lane == 0) {
        outI[(size_t)rg * KSEL + kk] = (float)idx;
        outW[(size_t)rg * KSEL + kk] = wsel * ROUTE_SCALE_;
      }
      if (lane == idx) prob = -1.0f;
    }
  }
}

extern "C" void kernel_launch(void* const* d_in, const int* in_sizes, int n_in,
                              void* d_out, int out_size, void* d_ws, size_t ws_size,
                              hipStream_t stream) {
  const float* x = (const float*)d_in[0];
  const float* W = (const float*)d_in[1];
  float* WT = (float*)d_ws;                 // 2048*64*4 = 524288 bytes
  float* out = (float*)d_out;
  wtrans_kernel<<<dim3(512), dim3(256), 0, stream>>>(W, WT);
  gate_kernel<<<dim3(T_ / 64), dim3(256), 0, stream>>>(x, WT, out);
}

// Round 10
// 134.189 us; speedup vs baseline: 4.0045x; 4.0045x over previous
//
#include <hip/hip_runtime.h>

typedef float f32x4 __attribute__((ext_vector_type(4)));
typedef short bf16x8 __attribute__((ext_vector_type(8)));
typedef unsigned int u32;
typedef unsigned short u16;

constexpr int T_ = 32768;
constexpr int D_ = 2048;
constexpr int E_ = 64;
constexpr int KSEL = 6;
constexpr float ROUTE_SCALE_ = 1.0f;

constexpr int ROWS = 64;            // 4 waves x 16 rows per block
constexpr int DK = 64;              // k per chunk
constexpr int NCH = D_ / DK;        // 32
constexpr int WBUF = 24576;         // one W chunk: 24 frags x 1KB (3 planes x 8 frags)
constexpr int LGT_OFF = 2 * WBUF;   // 49152; + 16KB logits slabs = 65536 LDS

// round-to-nearest-even fp32 -> bf16 (R4's split; gives logits BIT-IDENTICAL to the
// passing R4 kernel. R6-R9 used truncation here -> different logit bits -> a near-tie
// top-k flip (deterministic absmax 8.0). Numerics, not structure, was the failure.)
__device__ __forceinline__ u16 f2bf(float f) {
  u32 u = __float_as_uint(f);
  return (u16)((u + 0x7fffu + ((u >> 16) & 1u)) >> 16);
}
__device__ __forceinline__ float bf2f(u16 h) { return __uint_as_float(((u32)h) << 16); }

// ---- W pre-split into MFMA-fragment-ordered 3-plane bf16 ----
// byte: c*WBUF + ((kf*4+nfq)*3 + p)*1024 + lane*16
// lane elem j = plane_p(W[e][k]), e = nfq*16+(lane&15), k = c*64 + kf*32 + (lane>>4)*8 + j
__global__ void wsplit_kernel(const float* __restrict__ W, char* __restrict__ ws) {
  int g = blockIdx.x * 256 + threadIdx.x;
  if (g >= NCH * 512) return;                  // exactly 16384 threads do work
  int lane = g & 63, nfq = (g >> 6) & 3, kf = (g >> 8) & 1, c = g >> 9;
  int e = nfq * 16 + (lane & 15);
  int k0 = c * 64 + kf * 32 + ((lane >> 4) << 3);
  const float* src = W + (size_t)e * D_ + k0;
  f32x4 a0 = *(const f32x4*)src;
  f32x4 a1 = *(const f32x4*)(src + 4);
  float f[8] = {a0.x, a0.y, a0.z, a0.w, a1.x, a1.y, a1.z, a1.w};
  bf16x8 h, m, l;
#pragma unroll
  for (int j = 0; j < 8; ++j) {
    u16 hb = f2bf(f[j]); float r1 = f[j] - bf2f(hb);   // exact
    u16 mb = f2bf(r1);   float r2 = r1 - bf2f(mb);     // exact
    u16 lb = f2bf(r2);
    h[j] = (short)hb; m[j] = (short)mb; l[j] = (short)lb;
  }
  char* dst = ws + (size_t)c * WBUF + (size_t)((kf * 4 + nfq) * 3) * 1024 + lane * 16;
  *(bf16x8*)(dst)        = h;
  *(bf16x8*)(dst + 1024) = m;
  *(bf16x8*)(dst + 2048) = l;
}

__device__ __forceinline__ void gload16(const void* g, void* l) {
  __builtin_amdgcn_global_load_lds(
      (const __attribute__((address_space(1))) void*)g,
      (__attribute__((address_space(3))) void*)l, 16, 0, 0);
}

__launch_bounds__(256, 2)
__global__ void gate_kernel(const float* __restrict__ x, const char* __restrict__ ws,
                            float* __restrict__ out) {
  __shared__ __align__(16) char sm[LGT_OFF + ROWS * E_ * 4];  // 65536 B

  const int tid = threadIdx.x;
  const int lane = tid & 63;
  const int wv = tid >> 6;                 // 0..3, wave owns rows [wv*16, wv*16+16)
  const int r0 = blockIdx.x * ROWS;

  // per-lane x base: row = r0 + wv*16 + (lane&15), k-offset (lane>>4)*8
  const float* xp = x + (size_t)(r0 + wv * 16 + (lane & 15)) * D_ + ((lane >> 4) << 3);

  f32x4 xA[4], xB[4];                      // two static reg banks (chunk c, c+1)

#define XLOAD(BANK, C)                                            \
  { const float* p_ = xp + (size_t)(C) * DK;                      \
    BANK[0] = *(const f32x4*)(p_);      BANK[1] = *(const f32x4*)(p_ + 4);  \
    BANK[2] = *(const f32x4*)(p_ + 32); BANK[3] = *(const f32x4*)(p_ + 36); }

  // LDS dst wave-uniform (HW adds lane*16 itself, m104); global src per-lane.
  auto wgload = [&](int c) {
    const char* src = ws + (size_t)c * WBUF + (size_t)tid * 16;     // per-lane
    char* dstb = sm + (c & 1) * WBUF + (size_t)(wv * 64) * 16;      // wave-uniform
#pragma unroll
    for (int it = 0; it < 6; ++it)
      gload16(src + it * 4096, dstb + it * 4096);
  };

  f32x4 acc[4] = {};                       // 4 expert-quadrants x 4 regs

  // split one reg bank into A-frags (truncation, as R4) + 24 MFMA against wbuf[c&1]
#define STEP(BANK, C)                                                          \
  {                                                                            \
    bf16x8 ah[2], am[2], al[2];                                                \
    _Pragma("unroll")                                                          \
    for (int kf = 0; kf < 2; ++kf) {                                           \
      f32x4 a0 = BANK[2 * kf], a1 = BANK[2 * kf + 1];                          \
      float f[8] = {a0.x, a0.y, a0.z, a0.w, a1.x, a1.y, a1.z, a1.w};           \
      _Pragma("unroll")                                                        \
      for (int j = 0; j < 8; ++j) {                                            \
        float v = f[j];                                                        \
        u32 uh = __float_as_uint(v) & 0xffff0000u;                             \
        float r1 = v - __uint_as_float(uh);                                    \
        u32 um = __float_as_uint(r1) & 0xffff0000u;                            \
        float r2 = r1 - __uint_as_float(um);                                   \
        u32 ul = __float_as_uint(r2);                                          \
        ah[kf][j] = (short)(uh >> 16);                                         \
        am[kf][j] = (short)(um >> 16);                                         \
        al[kf][j] = (short)(ul >> 16);                                         \
      }                                                                        \
    }                                                                          \
    const char* wb = sm + ((C) & 1) * WBUF + lane * 16;                        \
    _Pragma("unroll")                                                          \
    for (int kf = 0; kf < 2; ++kf) {                                           \
      _Pragma("unroll")                                                        \
      for (int n = 0; n < 4; ++n) {                                            \
        const char* fb = wb + (size_t)((kf * 4 + n) * 3) * 1024;               \
        bf16x8 bh = *(const bf16x8*)(fb);                                      \
        bf16x8 bm = *(const bf16x8*)(fb + 1024);                               \
        bf16x8 bl = *(const bf16x8*)(fb + 2048);                               \
        f32x4 c_ = acc[n];                                                     \
        c_ = __builtin_amdgcn_mfma_f32_16x16x32_bf16(al[kf], bh, c_, 0, 0, 0); \
        c_ = __builtin_amdgcn_mfma_f32_16x16x32_bf16(am[kf], bm, c_, 0, 0, 0); \
        c_ = __builtin_amdgcn_mfma_f32_16x16x32_bf16(ah[kf], bl, c_, 0, 0, 0); \
        c_ = __builtin_amdgcn_mfma_f32_16x16x32_bf16(am[kf], bh, c_, 0, 0, 0); \
        c_ = __builtin_amdgcn_mfma_f32_16x16x32_bf16(ah[kf], bm, c_, 0, 0, 0); \
        c_ = __builtin_amdgcn_mfma_f32_16x16x32_bf16(ah[kf], bh, c_, 0, 0, 0); \
        acc[n] = c_;                                                           \
      }                                                                        \
    }                                                                          \
  }

  // prologue: x chunks 0,1 to reg banks; W chunk 0 to LDS buf0
  XLOAD(xA, 0)
  XLOAD(xB, 1)
  wgload(0);

  // main loop: one __syncthreads per chunk; every load it drains is >=1 phase old
  for (int cc = 0; cc < NCH; cc += 2) {
    __syncthreads();                       // W(cc) + x-bank loads landed
    if (cc + 1 < NCH) wgload(cc + 1);      // -> wbuf1 (last read compute(cc-1), drained)
    STEP(xA, cc)                           // compute chunk cc from wbuf0
    if (cc + 2 < NCH) XLOAD(xA, cc + 2)
    __syncthreads();                       // W(cc+1) landed
    if (cc + 2 < NCH) wgload(cc + 2);      // -> wbuf0
    STEP(xB, cc + 1)                       // compute chunk cc+1 from wbuf1
    if (cc + 3 < NCH) XLOAD(xB, cc + 3)
  }

  // ---- logits to wave-private slab (C/D: col=lane&15 -> expert, row=(lane>>4)*4+j) ----
  float* slab = (float*)(sm + LGT_OFF + wv * 16 * E_ * 4);
#pragma unroll
  for (int n = 0; n < 4; ++n)
#pragma unroll
    for (int j = 0; j < 4; ++j) {
      int r = ((lane >> 4) << 2) + j;
      slab[r * 64 + n * 16 + (lane & 15)] = acc[n][j];
    }

  // ---- proven top-k epilogue: lane = expert, 16 rows per wave ----
  float* outI = out;
  float* outW = out + (size_t)T_ * KSEL;
  for (int rr = 0; rr < 16; ++rr) {
    const float lg = slab[rr * 64 + lane];
    float mx = lg;
#pragma unroll
    for (int off = 32; off; off >>= 1) mx = fmaxf(mx, __shfl_xor(mx, off, 64));
    const float p = expf(lg - mx);
    float ssum = p;
#pragma unroll
    for (int off = 32; off; off >>= 1) ssum += __shfl_xor(ssum, off, 64);
    float prob = p / ssum;

    const int rg = r0 + wv * 16 + rr;
#pragma unroll
    for (int kk = 0; kk < KSEL; ++kk) {
      float v = prob; int idx = lane;
#pragma unroll
      for (int off = 32; off; off >>= 1) {
        float ov = __shfl_xor(v, off, 64);
        int oi = __shfl_xor(idx, off, 64);
        if (ov > v || (ov == v && oi < idx)) { v = ov; idx = oi; }
      }
      const float wsel = __shfl(lg, idx, 64);
      if (lane == 0) {
        outI[(size_t)rg * KSEL + kk] = (float)idx;
        outW[(size_t)rg * KSEL + kk] = wsel * ROUTE_SCALE_;
      }
      if (lane == idx) prob = -1.0f;
    }
  }
#undef XLOAD
#undef STEP
}

extern "C" void kernel_launch(void* const* d_in, const int* in_sizes, int n_in,
                              void* d_out, int out_size, void* d_ws, size_t ws_size,
                              hipStream_t stream) {
  const float* x = (const float*)d_in[0];
  const float* W = (const float*)d_in[1];
  char* ws = (char*)d_ws;                  // 32 * 24576 = 786432 bytes
  float* out = (float*)d_out;
  wsplit_kernel<<<dim3(64), dim3(256), 0, stream>>>(W, ws);
  gate_kernel<<<dim3(T_ / ROWS), dim3(256), 0, stream>>>(x, ws, out);
}